// Round 4
// baseline (52.051 us; speedup 1.0000x reference)
//
#include <hip/hip_runtime.h>

#define NX 4096
#define NY 2048
#define EPS 1e-8f
#define ROWS 16         // rows per wave strip (fully unrolled streaming loop)
#define CPW 63          // output columns per block
#define INV_D 0.001f

typedef float f32x2 __attribute__((ext_vector_type(2)));

__device__ __forceinline__ int clampi(int i, int lo, int hi) {
    return i < lo ? lo : (i > hi ? hi : i);
}

// Packed (2-wide) one-rcp WENO5: component .x = fe face, .y = fn face.
// <2 x float> ops lower to v_pk_{add,mul,fma}_f32 on gfx950.
__device__ __forceinline__ f32x2 weno5_pk(f32x2 qm2, f32x2 qm1, f32x2 q0,
                                          f32x2 qp1, f32x2 qp2) {
    f32x2 f1 = (1.0f/3.0f)*qm2 - (7.0f/6.0f)*qm1 + (11.0f/6.0f)*q0;
    f32x2 f2 = (-1.0f/6.0f)*qm1 + (5.0f/6.0f)*q0 + (1.0f/3.0f)*qp1;
    f32x2 f3 = (1.0f/3.0f)*q0 + (5.0f/6.0f)*qp1 - (1.0f/6.0f)*qp2;
    f32x2 d1 = qm2 - 2.0f*qm1 + q0;
    f32x2 e1 = qm2 - 4.0f*qm1 + 3.0f*q0;
    f32x2 d2 = qm1 - 2.0f*q0 + qp1;
    f32x2 e2 = qm1 - qp1;
    f32x2 d3 = q0 - 2.0f*qp1 + qp2;
    f32x2 e3 = 3.0f*q0 - 4.0f*qp1 + qp2;
    const float k1 = 13.0f/12.0f, k2 = 0.25f;
    f32x2 b1 = k1*(d1*d1) + k2*(e1*e1);
    f32x2 b2 = k1*(d2*d2) + k2*(e2*e2);
    f32x2 b3 = k1*(d3*d3) + k2*(e3*e3);
    f32x2 t1 = b1 + EPS, t2 = b2 + EPS, t3 = b3 + EPS;
    f32x2 p23 = t2*t3, p13 = t1*t3, p12 = t1*t2;
    f32x2 w1 = 0.1f*(p23*p23);
    f32x2 w2 = 0.6f*(p13*p13);
    f32x2 w3 = 0.3f*(p12*p12);
    f32x2 num = w1*f1 + w2*f2 + w3*f3;
    f32x2 den = (w1 + w2) + w3;
    f32x2 rc;
    rc.x = __builtin_amdgcn_rcpf(den.x);
    rc.y = __builtin_amdgcn_rcpf(den.y);
    return num * rc;
}

// One wave strip: 16 rows x 63 output columns. EDGE path carries all clamps
// and guards; interior path is pure base+immediate-offset addressing.
template <bool EDGE>
__device__ __forceinline__ void run_strip(const float* __restrict__ h,
                                          const float* __restrict__ u,
                                          const float* __restrict__ v,
                                          float* __restrict__ out,
                                          int x0, int y0w, int lane) {
    const int xf = x0 - 1 + lane;                       // x-face this lane owns
    const int xo = x0 + lane;                           // output column
    const int xc = EDGE ? (xo < NX ? xo : NX - 1) : xo; // column for fn path
    const int xq = EDGE ? clampi(xf, 0, NX - 1) : xf;   // column for u loads

    int xs[6];
    if (EDGE) {
#pragma unroll
        for (int k = 0; k < 6; ++k) xs[k] = clampi(xf - 2 + k, 0, NX - 1);
    }

    // ---- rolling 6-deep h-column window: hw[k] = h[y-3+k][xc] at row y.
    float hw[6];
#pragma unroll
    for (int k = 0; k < 6; ++k) {
        int yy = EDGE ? clampi(y0w - 3 + k, 0, NY - 1) : (y0w - 3 + k);
        hw[k] = h[(size_t)yy * NX + xc];
    }
    // fn_prev = flux at face y0w-1 (cells y0w-3 .. y0w+2 = hw[0..5]).
    float fn_prev;
    {
        int fy = EDGE ? clampi(y0w - 1, 0, NY - 1) : (y0w - 1);
        float vv = v[(size_t)fy * NX + xc];
        bool vp = (vv >= 0.0f);
        f32x2 a = { vp ? hw[0] : hw[5], vp ? hw[0] : hw[5] };
        f32x2 b = { vp ? hw[1] : hw[4], vp ? hw[1] : hw[4] };
        f32x2 c = { vp ? hw[2] : hw[3], vp ? hw[2] : hw[3] };
        f32x2 d = { vp ? hw[3] : hw[2], vp ? hw[3] : hw[2] };
        f32x2 e = { vp ? hw[4] : hw[1], vp ? hw[4] : hw[1] };
        fn_prev = vv * weno5_pk(a, b, c, d, e).x;
    }

#pragma unroll
    for (int r = 0; r < ROWS; ++r) {
        const int y = y0w + r;
        const size_t rowb = (size_t)y * NX;

        // x-stencil: h[y][xf-2 .. xf+3]
        float r0, r1, r2, r3, r4, r5;
        if (EDGE) {
            const float* hr = h + rowb;
            r0 = hr[xs[0]]; r1 = hr[xs[1]]; r2 = hr[xs[2]];
            r3 = hr[xs[3]]; r4 = hr[xs[4]]; r5 = hr[xs[5]];
        } else {
            const float* hr = h + rowb + xf;
            r0 = hr[-2]; r1 = hr[-1]; r2 = hr[0];
            r3 = hr[1];  r4 = hr[2];  r5 = hr[3];
        }
        float uval = __builtin_nontemporal_load(u + rowb + xq);
        float vval = __builtin_nontemporal_load(v + rowb + xc);
        // advance column window: need h[y+3][xc]
        int yy = EDGE ? clampi(y + 3, 0, NY - 1) : (y + 3);
        float hwn = h[(size_t)yy * NX + xc];

        bool up = (uval >= 0.0f);
        bool vp = (vval >= 0.0f);
        // fe stencil cells xf-2..xf+3 = r0..r5 ; fn cells y-2..y+3 = hw[1..5],hwn
        f32x2 a = { up ? r0 : r5, vp ? hw[1] : hwn   };
        f32x2 b = { up ? r1 : r4, vp ? hw[2] : hw[5] };
        f32x2 c = { up ? r2 : r3, vp ? hw[3] : hw[4] };
        f32x2 d = { up ? r3 : r2, vp ? hw[4] : hw[3] };
        f32x2 e = { up ? r4 : r1, vp ? hw[5] : hw[2] };
        f32x2 q = weno5_pk(a, b, c, d, e);
        float fe = uval * q.x;
        float fn_cur = vval * q.y;

        float fe_r = __shfl_down(fe, 1);   // face at column xo
        float val = ((fe - fe_r) + (fn_prev - fn_cur)) * INV_D;  // = -div

        if (EDGE) {
            if (xo < 2 || xo >= NX - 2 || y < 2 || y >= NY - 2) val = 0.0f;
            if (lane < CPW && xo < NX)
                __builtin_nontemporal_store(val, out + rowb + xo);
        } else {
            if (lane < CPW)
                __builtin_nontemporal_store(val, out + rowb + xo);
        }

        // shift window
        hw[0] = hw[1]; hw[1] = hw[2]; hw[2] = hw[3];
        hw[3] = hw[4]; hw[4] = hw[5]; hw[5] = hwn;
        fn_prev = fn_cur;
    }
}

__global__ __launch_bounds__(256) void adv_kernel(const float* __restrict__ h,
                                                  const float* __restrict__ u,
                                                  const float* __restrict__ v,
                                                  float* __restrict__ out) {
    const int lane = threadIdx.x & 63;
    const int wid  = threadIdx.x >> 6;
    const int x0 = blockIdx.x * CPW;
    const int y0w = (blockIdx.y * 4 + wid) * ROWS;

    // Edge blocks: x0==0 (left clamps), blockIdx.x>=64 (right stencil reaches
    // beyond NX-1 for xf>=4093, plus tail columns), first/last row-band.
    const bool edge = (blockIdx.x == 0) || (blockIdx.x >= 64) ||
                      (blockIdx.y == 0) || (blockIdx.y == gridDim.y - 1);
    if (edge)
        run_strip<true>(h, u, v, out, x0, y0w, lane);
    else
        run_strip<false>(h, u, v, out, x0, y0w, lane);
}

extern "C" void kernel_launch(void* const* d_in, const int* in_sizes, int n_in,
                              void* d_out, int out_size, void* d_ws, size_t ws_size,
                              hipStream_t stream) {
    const float* h = (const float*)d_in[0];
    const float* u = (const float*)d_in[1];
    const float* v = (const float*)d_in[2];
    float* out = (float*)d_out;

    dim3 block(256, 1, 1);
    dim3 grid((NX + CPW - 1) / CPW, NY / (4 * ROWS), 1);  // 66 x 32
    adv_kernel<<<grid, block, 0, stream>>>(h, u, v, out);
}

// Round 5
// 38.875 us; speedup vs baseline: 1.3389x; 1.3389x over previous
//
#include <hip/hip_runtime.h>

#define NX 4096
#define NY 2048
#define EPS 1e-8f
#define ROWS 8          // rows per wave strip
#define CPW 63          // output columns per block
#define INV_D 0.001f

typedef float f32x2 __attribute__((ext_vector_type(2)));

__device__ __forceinline__ int clampi(int i, int lo, int hi) {
    return i < lo ? lo : (i > hi ? hi : i);
}

// Scalar one-rcp WENO5 (used once per strip for the leading fn face).
__device__ __forceinline__ float weno5_s(float qm2, float qm1, float q0,
                                         float qp1, float qp2) {
    float f1 = fmaf(1.0f/3.0f, qm2, fmaf(-7.0f/6.0f, qm1, (11.0f/6.0f)*q0));
    float f2 = fmaf(-1.0f/6.0f, qm1, fmaf(5.0f/6.0f, q0, (1.0f/3.0f)*qp1));
    float f3 = fmaf(1.0f/3.0f, q0, fmaf(5.0f/6.0f, qp1, (-1.0f/6.0f)*qp2));
    const float k1 = 13.0f/12.0f, k2 = 0.25f;
    float d1 = qm2 - 2.0f*qm1 + q0,  e1 = qm2 - 4.0f*qm1 + 3.0f*q0;
    float d2 = qm1 - 2.0f*q0 + qp1,  e2 = qm1 - qp1;
    float d3 = q0 - 2.0f*qp1 + qp2,  e3 = 3.0f*q0 - 4.0f*qp1 + qp2;
    float b1 = fmaf(k1, d1*d1, k2*(e1*e1));
    float b2 = fmaf(k1, d2*d2, k2*(e2*e2));
    float b3 = fmaf(k1, d3*d3, k2*(e3*e3));
    float t1 = b1 + EPS, t2 = b2 + EPS, t3 = b3 + EPS;
    float p23 = t2*t3, p13 = t1*t3, p12 = t1*t2;
    float w1 = 0.1f*(p23*p23), w2 = 0.6f*(p13*p13), w3 = 0.3f*(p12*p12);
    float num = fmaf(w1, f1, fmaf(w2, f2, w3*f3));
    return num * __builtin_amdgcn_rcpf((w1 + w2) + w3);
}

// Packed (2-wide) one-rcp WENO5: .x = fe face, .y = fn face.
__device__ __forceinline__ f32x2 weno5_pk(f32x2 qm2, f32x2 qm1, f32x2 q0,
                                          f32x2 qp1, f32x2 qp2) {
    f32x2 f1 = (1.0f/3.0f)*qm2 - (7.0f/6.0f)*qm1 + (11.0f/6.0f)*q0;
    f32x2 f2 = (-1.0f/6.0f)*qm1 + (5.0f/6.0f)*q0 + (1.0f/3.0f)*qp1;
    f32x2 f3 = (1.0f/3.0f)*q0 + (5.0f/6.0f)*qp1 - (1.0f/6.0f)*qp2;
    f32x2 d1 = qm2 - 2.0f*qm1 + q0;
    f32x2 e1 = qm2 - 4.0f*qm1 + 3.0f*q0;
    f32x2 d2 = qm1 - 2.0f*q0 + qp1;
    f32x2 e2 = qm1 - qp1;
    f32x2 d3 = q0 - 2.0f*qp1 + qp2;
    f32x2 e3 = 3.0f*q0 - 4.0f*qp1 + qp2;
    const float k1 = 13.0f/12.0f, k2 = 0.25f;
    f32x2 b1 = k1*(d1*d1) + k2*(e1*e1);
    f32x2 b2 = k1*(d2*d2) + k2*(e2*e2);
    f32x2 b3 = k1*(d3*d3) + k2*(e3*e3);
    f32x2 t1 = b1 + EPS, t2 = b2 + EPS, t3 = b3 + EPS;
    f32x2 p23 = t2*t3, p13 = t1*t3, p12 = t1*t2;
    f32x2 w1 = 0.1f*(p23*p23);
    f32x2 w2 = 0.6f*(p13*p13);
    f32x2 w3 = 0.3f*(p12*p12);
    f32x2 num = w1*f1 + w2*f2 + w3*f3;
    f32x2 den = (w1 + w2) + w3;
    f32x2 rc;
    rc.x = __builtin_amdgcn_rcpf(den.x);
    rc.y = __builtin_amdgcn_rcpf(den.y);
    return num * rc;
}

// One wave strip: 8 rows x 63 output columns. Phase 1 batches ALL global
// loads into register arrays (79 independent loads -> latency amortized);
// phase 2 is pure VALU + one shuffle per row.
template <bool EDGE>
__device__ __forceinline__ void run_strip(const float* __restrict__ h,
                                          const float* __restrict__ u,
                                          const float* __restrict__ v,
                                          float* __restrict__ out,
                                          int x0, int y0w, int lane) {
    const int xf = x0 - 1 + lane;                       // x-face this lane owns
    const int xo = x0 + lane;                           // output column
    const int xc = EDGE ? (xo < NX ? xo : NX - 1) : xo; // column for fn path
    const int xq = EDGE ? clampi(xf, 0, NX - 1) : xf;   // column for u loads

    int xs[6];
    if (EDGE) {
#pragma unroll
        for (int k = 0; k < 6; ++k) xs[k] = clampi(xf - 2 + k, 0, NX - 1);
    }

    // ================= phase 1: batched loads =================
    float col[ROWS + 6];                 // h column xc, rows y0w-3 .. y0w+10
#pragma unroll
    for (int k = 0; k < ROWS + 6; ++k) {
        int yy = EDGE ? clampi(y0w - 3 + k, 0, NY - 1) : (y0w - 3 + k);
        col[k] = h[(size_t)yy * NX + xc];
    }
    float uu[ROWS];                      // u[y][xf], rows always in-range
#pragma unroll
    for (int r = 0; r < ROWS; ++r)
        uu[r] = u[(size_t)(y0w + r) * NX + xq];
    float vv[ROWS + 1];                  // v at face rows y0w-1 .. y0w+7
#pragma unroll
    for (int j = 0; j <= ROWS; ++j) {
        int fy = EDGE ? clampi(y0w - 1 + j, 0, NY - 1) : (y0w - 1 + j);
        vv[j] = v[(size_t)fy * NX + xc];
    }
    float st[ROWS][6];                   // h[y][xf-2 .. xf+3] per row
#pragma unroll
    for (int r = 0; r < ROWS; ++r) {
        const float* hr = h + (size_t)(y0w + r) * NX;
        if (EDGE) {
#pragma unroll
            for (int k = 0; k < 6; ++k) st[r][k] = hr[xs[k]];
        } else {
#pragma unroll
            for (int k = 0; k < 6; ++k) st[r][k] = hr[xf - 2 + k];
        }
    }

    // ================= phase 2: compute =================
    // leading fn face at y0w-1: cells col[0..5], vel vv[0]
    float fn_prev;
    {
        float vl = vv[0];
        bool vp = (vl >= 0.0f);
        fn_prev = vl * weno5_s(vp ? col[0] : col[5], vp ? col[1] : col[4],
                               vp ? col[2] : col[3], vp ? col[3] : col[2],
                               vp ? col[4] : col[1]);
    }

#pragma unroll
    for (int r = 0; r < ROWS; ++r) {
        const int y = y0w + r;
        float uval = uu[r];
        float vval = vv[r + 1];
        bool up = (uval >= 0.0f);
        bool vp = (vval >= 0.0f);
        // fe cells xf-2..xf+3 = st[r][0..5]; fn cells y-2..y+3 = col[r+1..r+6]
        f32x2 a = { up ? st[r][0] : st[r][5], vp ? col[r+1] : col[r+6] };
        f32x2 b = { up ? st[r][1] : st[r][4], vp ? col[r+2] : col[r+5] };
        f32x2 c = { up ? st[r][2] : st[r][3], vp ? col[r+3] : col[r+4] };
        f32x2 d = { up ? st[r][3] : st[r][2], vp ? col[r+4] : col[r+3] };
        f32x2 e = { up ? st[r][4] : st[r][1], vp ? col[r+5] : col[r+2] };
        f32x2 q = weno5_pk(a, b, c, d, e);
        float fe = uval * q.x;            // face at column xo-1
        float fn_cur = vval * q.y;        // face at row y
        float fe_r = __shfl_down(fe, 1);  // face at column xo
        float val = ((fe - fe_r) + (fn_prev - fn_cur)) * INV_D;  // = -div

        if (EDGE) {
            if (xo < 2 || xo >= NX - 2 || y < 2 || y >= NY - 2) val = 0.0f;
            if (lane < CPW && xo < NX)
                __builtin_nontemporal_store(val, out + (size_t)y * NX + xo);
        } else {
            if (lane < CPW)
                __builtin_nontemporal_store(val, out + (size_t)y * NX + xo);
        }
        fn_prev = fn_cur;
    }
}

__global__ __launch_bounds__(256) void adv_kernel(const float* __restrict__ h,
                                                  const float* __restrict__ u,
                                                  const float* __restrict__ v,
                                                  float* __restrict__ out) {
    const int lane = threadIdx.x & 63;
    const int wid  = threadIdx.x >> 6;
    const int x0 = blockIdx.x * CPW;
    const int y0w = (blockIdx.y * 4 + wid) * ROWS;

    const bool edge = (blockIdx.x == 0) || (blockIdx.x >= 64) ||
                      (blockIdx.y == 0) || (blockIdx.y == gridDim.y - 1);
    if (edge)
        run_strip<true>(h, u, v, out, x0, y0w, lane);
    else
        run_strip<false>(h, u, v, out, x0, y0w, lane);
}

extern "C" void kernel_launch(void* const* d_in, const int* in_sizes, int n_in,
                              void* d_out, int out_size, void* d_ws, size_t ws_size,
                              hipStream_t stream) {
    const float* h = (const float*)d_in[0];
    const float* u = (const float*)d_in[1];
    const float* v = (const float*)d_in[2];
    float* out = (float*)d_out;

    dim3 block(256, 1, 1);
    dim3 grid((NX + CPW - 1) / CPW, NY / (4 * ROWS), 1);  // 66 x 64
    adv_kernel<<<grid, block, 0, stream>>>(h, u, v, out);
}